// Round 2
// baseline (1448.011 us; speedup 1.0000x reference)
//
#include <hip/hip_runtime.h>
#include <hip/hip_bf16.h>

#define NV 16384
#define NC 16
#define NL 6
#define ND 64

typedef unsigned short u16;
typedef unsigned int u32;

__device__ __forceinline__ float ldbf(const u16* __restrict__ p, int i) {
  return __uint_as_float(((u32)p[i]) << 16);
}

// ---- workspace layout (in floats, from start of d_ws) ----
// [0..64)      : int flags  (flags[0]=fdt: 1=bf16 inputs, 0=f32; flags[1]=bdt: 1=int8 bools)
// [64..)       : fp32 params, offsets below (relative to pbuf = ws+64)
#define OFF_WN   0
#define OFF_BN   4096
#define OFF_FE   4160
#define OFF_W1V  4224
#define OFF_B1V  28800
#define OFF_W2V  28864
#define OFF_B2V  53440
#define OFF_W1C  53504
#define OFF_B1C  119040
#define OFF_W2C  119104
#define OFF_B2C  184640
#define PARAMS_TOTAL 184704
#define OFF_VARSF (64 + PARAMS_TOTAL)            // 1,048,576 floats
#define OFF_NEGV  (OFF_VARSF + NV * ND)          // (NV+1)*64 floats

// Kernel A: sniff dtypes + convert all small params to fp32.
__global__ __launch_bounds__(256) void k_prep(
    const void* vars, const void* vval,
    const void* Wn, const void* bn, const void* femb,
    const void* W1v, const void* b1v, const void* W2v, const void* b2v,
    const void* W1c, const void* b1c, const void* W2c, const void* b2c,
    int* flags, float* pbuf) {
  __shared__ int sf;
  if (threadIdx.x == 0) {
    const u32* w = (const u32*)vars;
    int cnt = 0;
    for (int i = 0; i < 256; i++) {
      u32 e = (w[i] >> 7) & 0xFF;
      cnt += (e >= 0x6E && e <= 0x8E) ? 1 : 0;
    }
    int fdt = (cnt >= 192) ? 1 : 0;   // bf16 if low-halfword exponents look sane
    const u32* b = (const u32*)vval;
    int big = 0;
    for (int i = 0; i < 256; i++) big |= (b[i] > 1u) ? 1 : 0;
    flags[0] = fdt;
    flags[1] = big;                   // byte-packed bools
    sf = fdt;
  }
  __syncthreads();
  const int fdt = sf;
  const int tid = threadIdx.x;

  const void* src[11] = {Wn, bn, femb, W1v, b1v, W2v, b2v, W1c, b1c, W2c, b2c};
  const int   cnt[11] = {4096, 64, 64, 24576, 64, 24576, 64, 65536, 64, 65536, 64};
  const int   off[11] = {OFF_WN, OFF_BN, OFF_FE, OFF_W1V, OFF_B1V, OFF_W2V, OFF_B2V,
                         OFF_W1C, OFF_B1C, OFF_W2C, OFF_B2C};
  for (int j = 0; j < 11; j++) {
    const u16* pb = (const u16*)src[j];
    const float* pf = (const float*)src[j];
    float* dst = pbuf + off[j];
    for (int i = tid; i < cnt[j]; i += 256)
      dst[i] = fdt ? ldbf(pb, i) : pf[i];
  }
}

// Kernel B: convert variables to fp32.
__global__ __launch_bounds__(256) void k_cvt(const void* vars, const int* __restrict__ flags,
                                             float* __restrict__ varsF) {
  const int fdt = flags[0];
  const int i = blockIdx.x * 256 + threadIdx.x;
  varsF[i] = fdt ? ldbf((const u16*)vars, i) : ((const float*)vars)[i];
}

// Kernel C: negvar[r] = row_r @ Wn + bn; row NV uses false_emb (== true_emb).
__global__ __launch_bounds__(256) void k_negvar(
    const float* __restrict__ varsF, const float* __restrict__ pbuf,
    float* __restrict__ negvar) {
  __shared__ __align__(16) float Xr[16 * 64];
  const int tid = threadIdx.x, lane = tid & 63, wv = tid >> 6;
  const int rowbase = blockIdx.x * 16;
  for (int rr = wv; rr < 16; rr += 4) {
    const int R = rowbase + rr;
    float x = 0.f;
    if (R < NV) x = varsF[R * 64 + lane];
    else if (R == NV) x = pbuf[OFF_FE + lane];
    Xr[rr * 64 + lane] = x;
  }
  __syncthreads();
  float acc[4] = {0.f, 0.f, 0.f, 0.f};
  for (int k = 0; k < 64; k++) {
    const float w = pbuf[OFF_WN + k * 64 + lane];
#pragma unroll
    for (int j = 0; j < 4; j++) acc[j] += Xr[(wv * 4 + j) * 64 + k] * w;
  }
  const float bnl = pbuf[OFF_BN + lane];
#pragma unroll
  for (int j = 0; j < 4; j++) {
    const int R = rowbase + wv * 4 + j;
    if (R <= NV) negvar[R * 64 + lane] = acc[j] + bnl;
  }
}

__device__ __forceinline__ int ldmask(const void* p, int i, int bdt) {
  return bdt ? (int)((const signed char*)p)[i] : ((const int*)p)[i];
}

// Kernel D: fused gather -> clause combiner -> clause padding -> var combiner.
// One block (256 threads) handles 2 variables.
__global__ __launch_bounds__(256) void k_main(
    const float* __restrict__ varsF, const int* __restrict__ lits,
    const void* __restrict__ negm, const void* __restrict__ vval,
    const void* __restrict__ cval,
    const float* __restrict__ pbuf, const float* __restrict__ negvar,
    const int* __restrict__ flags, void* __restrict__ outv) {
  __shared__ __align__(16) float Xs[2 * 16 * 384];  // reused as pd[2][2][4][64] in phase D
  __shared__ __align__(16) float Ys[2 * 16 * 64];
  __shared__ int cvalS[32];

  const int tid = threadIdx.x, lane = tid & 63, wv = tid >> 6;
  const int v0 = blockIdx.x * 2;
  const int fdt = flags[0], bdt = flags[1];

  if (tid < 32) {
    const int u = tid >> 4, c = tid & 15;
    cvalS[tid] = ldmask(cval, (v0 + u) * NC + c, bdt);
  }

  const float false_l = pbuf[OFF_FE + lane];
  const float true_l = negvar[NV * 64 + lane];
  const float b1v_l = pbuf[OFF_B1V + lane], b2v_l = pbuf[OFF_B2V + lane];
  const float b1c_l = pbuf[OFF_B1C + lane], b2c_l = pbuf[OFF_B2C + lane];

  // Phase B: gather X[u][c][l*64+lane]. 192 segments, wave-uniform control.
  for (int s = wv; s < 192; s += 4) {
    const int u = s / 96;
    const int rem = s - u * 96;
    const int c = rem / 6;
    const int l = rem - c * 6;
    const int base = ((v0 + u) * NC + c) * NL + l;
    float x;
    if (!ldmask(vval, base, bdt)) {
      x = false_l;
    } else {
      const int idx = lits[base];
      x = ldmask(negm, base, bdt) ? negvar[idx * 64 + lane] : varsF[idx * 64 + lane];
    }
    Xs[(u * 16 + c) * 384 + l * 64 + lane] = x;
  }
  __syncthreads();

  // Phase C: clause combiner. Wave wv owns rows r = wv*8 .. wv*8+7 (r = u*16+c).
  float acc1[8], acc2[8];
#pragma unroll
  for (int j = 0; j < 8; j++) { acc1[j] = 0.f; acc2[j] = 0.f; }
  const float* Xrow = &Xs[(wv * 8) * 384];
  const float* W1vF = pbuf + OFF_W1V;
  const float* W2vF = pbuf + OFF_W2V;
  for (int k0 = 0; k0 < 384; k0 += 4) {
    float w1[4], w2[4];
#pragma unroll
    for (int i = 0; i < 4; i++) {
      w1[i] = W1vF[(k0 + i) * 64 + lane];
      w2[i] = W2vF[(k0 + i) * 64 + lane];
    }
#pragma unroll
    for (int j = 0; j < 8; j++) {
      const float4 xv = *(const float4*)(Xrow + j * 384 + k0);
      acc1[j] += xv.x * w1[0]; acc1[j] += xv.y * w1[1];
      acc1[j] += xv.z * w1[2]; acc1[j] += xv.w * w1[3];
      acc2[j] += xv.x * w2[0]; acc2[j] += xv.y * w2[1];
      acc2[j] += xv.z * w2[2]; acc2[j] += xv.w * w2[3];
    }
  }
#pragma unroll
  for (int j = 0; j < 8; j++) {
    const int r = wv * 8 + j;
    const float h = 1.0f / (1.0f + __expf(-(acc1[j] + b1v_l))) + acc2[j] + b2v_l;
    float s = h * h;
#pragma unroll
    for (int off = 32; off >= 1; off >>= 1) s += __shfl_xor(s, off, 64);
    float hn = h * (1.0f / sqrtf(s));
    if (!cvalS[r]) hn = true_l;
    Ys[r * 64 + lane] = hn;
  }
  __syncthreads();

  // Phase D: variable combiner. Wave wv owns K-chunk [wv*256, wv*256+256).
  float a1[2] = {0.f, 0.f}, a2[2] = {0.f, 0.f};
  const int kb = wv * 256;
  const float* W1cF = pbuf + OFF_W1C;
  const float* W2cF = pbuf + OFF_W2C;
  for (int kk = 0; kk < 256; kk += 4) {
    const int k = kb + kk;
    float w1[4], w2[4];
#pragma unroll
    for (int i = 0; i < 4; i++) {
      w1[i] = W1cF[(k + i) * 64 + lane];
      w2[i] = W2cF[(k + i) * 64 + lane];
    }
    const float4 y0 = *(const float4*)&Ys[k];
    const float4 y1 = *(const float4*)&Ys[1024 + k];
    a1[0] += y0.x * w1[0]; a1[0] += y0.y * w1[1]; a1[0] += y0.z * w1[2]; a1[0] += y0.w * w1[3];
    a2[0] += y0.x * w2[0]; a2[0] += y0.y * w2[1]; a2[0] += y0.z * w2[2]; a2[0] += y0.w * w2[3];
    a1[1] += y1.x * w1[0]; a1[1] += y1.y * w1[1]; a1[1] += y1.z * w1[2]; a1[1] += y1.w * w1[3];
    a2[1] += y1.x * w2[0]; a2[1] += y1.y * w2[1]; a2[1] += y1.z * w2[2]; a2[1] += y1.w * w2[3];
  }
  float* pd = Xs;  // [u][mat][wv][64], 4 KB, aliases Xs (safe: barrier above)
#pragma unroll
  for (int u = 0; u < 2; u++) {
    pd[((u * 2 + 0) * 4 + wv) * 64 + lane] = a1[u];
    pd[((u * 2 + 1) * 4 + wv) * 64 + lane] = a2[u];
  }
  __syncthreads();

  if (tid < 128) {
    const int u = tid >> 6, d = tid & 63;
    const int b0 = (u * 2 + 0) * 4, b1 = (u * 2 + 1) * 4;
    const float h1 = pd[(b0 + 0) * 64 + d] + pd[(b0 + 1) * 64 + d] +
                     pd[(b0 + 2) * 64 + d] + pd[(b0 + 3) * 64 + d] + b1c_l;
    const float h2 = pd[(b1 + 0) * 64 + d] + pd[(b1 + 1) * 64 + d] +
                     pd[(b1 + 2) * 64 + d] + pd[(b1 + 3) * 64 + d] + b2c_l;
    const float h = 1.0f / (1.0f + __expf(-h1)) + h2;
    float s = h * h;
#pragma unroll
    for (int off = 32; off >= 1; off >>= 1) s += __shfl_xor(s, off, 64);
    float o = h * (1.0f / sqrtf(s));
    bool hasc = false;
#pragma unroll
    for (int c = 0; c < 16; c++) hasc = hasc || (cvalS[u * 16 + c] != 0);
    if (!hasc) o = varsF[(v0 + u) * 64 + d];
    const int oi = (v0 + u) * 64 + d;
    if (fdt) ((__hip_bfloat16*)outv)[oi] = __float2bfloat16(o);
    else     ((float*)outv)[oi] = o;
  }
}

extern "C" void kernel_launch(void* const* d_in, const int* in_sizes, int n_in,
                              void* d_out, int out_size, void* d_ws, size_t ws_size,
                              hipStream_t stream) {
  const void* vars = d_in[0];
  const int* lits = (const int*)d_in[1];
  const void* negm = d_in[2];
  const void* vval = d_in[3];
  const void* cvalid = d_in[4];
  const void* Wn = d_in[5];
  const void* bn = d_in[6];
  const void* femb = d_in[7];
  const void* W1v = d_in[8];
  const void* b1v = d_in[9];
  const void* W2v = d_in[10];
  const void* b2v = d_in[11];
  const void* W1c = d_in[12];
  const void* b1c = d_in[13];
  const void* W2c = d_in[14];
  const void* b2c = d_in[15];

  float* ws = (float*)d_ws;
  int* flags = (int*)d_ws;
  float* pbuf = ws + 64;
  float* varsF = ws + OFF_VARSF;
  float* negvar = ws + OFF_NEGV;

  k_prep<<<1, 256, 0, stream>>>(vars, vval, Wn, bn, femb, W1v, b1v, W2v, b2v,
                                W1c, b1c, W2c, b2c, flags, pbuf);
  k_cvt<<<NV * ND / 256, 256, 0, stream>>>(vars, flags, varsF);
  k_negvar<<<(NV + 1 + 15) / 16, 256, 0, stream>>>(varsF, pbuf, negvar);
  k_main<<<NV / 2, 256, 0, stream>>>(varsF, lits, negm, vval, cvalid,
                                     pbuf, negvar, flags, d_out);
}

// Round 4
// 494.131 us; speedup vs baseline: 2.9304x; 2.9304x over previous
//
#include <hip/hip_runtime.h>
#include <hip/hip_bf16.h>

#define NV 16384
#define NC 16
#define NL 6
#define ND 64

typedef unsigned short u16;
typedef unsigned int u32;
typedef __attribute__((ext_vector_type(8))) short short8;
typedef __attribute__((ext_vector_type(4))) float f32x4;

// ---- pbuf (fp32) offsets, pbuf = (float*)((char*)ws + 256) ----
#define PB_BN  0
#define PB_FE  64
#define PB_B1V 128
#define PB_B2V 192
#define PB_B1C 256
#define PB_B2C 320
// ---- bf16 regions, offsets in u16 elements from (u16*)ws ----
#define U_BV    896       // [128][384]  Bv[n][k]: n<64 -> W1v[k][n], n>=64 -> W2v[k][n-64]
#define U_BC    50048     // [128][1024] same for W1c/W2c
#define U_BN    181120    // [64][64]    Bn[n][k] = Wn[k][n]
#define U_VARSB 185216    // [NV+1][64]  bf16 vars; row NV = false_emb
#define U_NEGB  1233856   // [NV+1][64]  bf16 negvar; row NV = true_emb
#define U_CE    2282496   // [NV][16][64] bf16 clause_emb

__device__ __forceinline__ float ldbf(const u16* p, int i) {
  return __uint_as_float(((u32)p[i]) << 16);
}
__device__ __forceinline__ u16 f2b(float f) {  // RNE f32->bf16
  u32 x = __float_as_uint(f);
  return (u16)((x + 0x7FFF + ((x >> 16) & 1)) >> 16);
}
__device__ __forceinline__ int ldmask(const void* p, int i, int bdt) {
  return bdt ? (int)((const signed char*)p)[i] : ((const int*)p)[i];
}
__device__ __forceinline__ float ldf(const void* p, int i, int fdt) {
  return fdt ? ldbf((const u16*)p, i) : ((const float*)p)[i];
}

// ---------- prep0: sniff dtypes, small fp32 params, varsB row NV ----------
__global__ __launch_bounds__(256) void k_prep0(
    const void* vars, const void* vval, const void* bn, const void* femb,
    const void* b1v, const void* b2v, const void* b1c, const void* b2c,
    int* flags, float* pbuf, u16* wsB) {
  __shared__ int sf;
  if (threadIdx.x == 0) {
    const u32* w = (const u32*)vars;
    int cnt = 0;
    for (int i = 0; i < 256; i++) {
      u32 e = (w[i] >> 7) & 0xFF;
      cnt += (e >= 0x6E && e <= 0x8E) ? 1 : 0;
    }
    int fdt = (cnt >= 192) ? 1 : 0;
    const u32* b = (const u32*)vval;
    int big = 0;
    for (int i = 0; i < 256; i++) big |= (b[i] > 1u) ? 1 : 0;
    flags[0] = fdt;
    flags[1] = big;
    sf = fdt;
  }
  __syncthreads();
  const int fdt = sf;
  const int tid = threadIdx.x;
  if (tid < 64) {
    const void* src[6] = {bn, femb, b1v, b2v, b1c, b2c};
    const int off[6] = {PB_BN, PB_FE, PB_B1V, PB_B2V, PB_B1C, PB_B2C};
    for (int j = 0; j < 6; j++) pbuf[off[j] + tid] = ldf(src[j], tid, fdt);
    // varsB row NV = false_emb (bf16)
    wsB[U_VARSB + NV * 64 + tid] = fdt ? ((const u16*)femb)[tid] : f2b(((const float*)femb)[tid]);
  }
}

// ---------- prepW: transpose big weights to bf16 [n][k] ----------
__global__ __launch_bounds__(256) void k_prepW(
    const void* W1v, const void* W2v, const void* W1c, const void* W2c,
    const void* Wn, const int* flags, u16* wsB) {
  const int fdt = flags[0];
  for (int i = blockIdx.x * 256 + threadIdx.x; i < 184320; i += 64 * 256) {
    if (i < 49152) {
      int n = i / 384, k = i - n * 384;
      const void* src = (n < 64) ? W1v : W2v;
      wsB[U_BV + i] = f2b(ldf(src, k * 64 + (n & 63), fdt));
    } else if (i < 180224) {
      int j = i - 49152;
      int n = j / 1024, k = j - n * 1024;
      const void* src = (n < 64) ? W1c : W2c;
      wsB[U_BC + j] = f2b(ldf(src, k * 64 + (n & 63), fdt));
    } else {
      int j = i - 180224;
      int n = j >> 6, k = j & 63;
      wsB[U_BN + j] = f2b(ldf(Wn, k * 64 + n, fdt));
    }
  }
}

// ---------- cvt: vars -> bf16 varsB rows 0..NV-1 ----------
__global__ __launch_bounds__(256) void k_cvt(const void* vars, const int* flags, u16* wsB) {
  const int fdt = flags[0];
  const int i = blockIdx.x * 256 + threadIdx.x;
  wsB[U_VARSB + i] = fdt ? ((const u16*)vars)[i] : f2b(((const float*)vars)[i]);
}

// ---------- negvar via MFMA: negB[r] = varsB[r] @ Wn + bn (row NV -> true_emb) ----------
__global__ __launch_bounds__(256) void k_negvar(const float* pbuf, u16* wsB) {
  const int tid = threadIdx.x, lane = tid & 63, wv = tid >> 6;
  const int col = lane & 15, quad = lane >> 4, q8 = quad * 8;
  const int rowbase = blockIdx.x * 64 + wv * 16;
  f32x4 acc[4];
#pragma unroll
  for (int nt = 0; nt < 4; nt++) acc[nt] = (f32x4){0.f, 0.f, 0.f, 0.f};
  const int arow = min(rowbase + col, NV);
#pragma unroll
  for (int ks = 0; ks < 2; ks++) {
    const short8 a = *(const short8*)(wsB + U_VARSB + arow * 64 + ks * 32 + q8);
#pragma unroll
    for (int nt = 0; nt < 4; nt++) {
      const short8 b = *(const short8*)(wsB + U_BN + (nt * 16 + col) * 64 + ks * 32 + q8);
      acc[nt] = __builtin_amdgcn_mfma_f32_16x16x32_bf16(a, b, acc[nt], 0, 0, 0);
    }
  }
#pragma unroll
  for (int reg = 0; reg < 4; reg++) {
    const int r = rowbase + quad * 4 + reg;
    if (r <= NV) {
#pragma unroll
      for (int nt = 0; nt < 4; nt++) {
        const int d = nt * 16 + col;
        wsB[U_NEGB + r * 64 + d] = f2b(acc[nt][reg] + pbuf[PB_BN + d]);
      }
    }
  }
}

// ---------- clause combiner: gather + MFMA + epilogue, wave-autonomous ----------
__global__ __launch_bounds__(256) void k_clause(
    const int* __restrict__ lits, const void* __restrict__ negm,
    const void* __restrict__ vval, const void* __restrict__ cval,
    const float* __restrict__ pbuf, const int* __restrict__ flags,
    u16* __restrict__ wsB) {
  __shared__ __align__(16) u16 Xs[4 * 16 * 392];  // per-wave 16 rows x 392 (pad)
  __shared__ int cvS[4][16];

  const int tid = threadIdx.x, lane = tid & 63, wv = tid >> 6;
  const int col = lane & 15, quad = lane >> 4, q8 = quad * 8;
  const int bdt = flags[1];
  const int v = blockIdx.x * 4 + wv;
  u16* XsW = Xs + wv * (16 * 392);

  if (lane < 16) cvS[wv][lane] = ldmask(cval, v * NC + lane, bdt);

  // gather: 96 segments (c,l), 2 per iteration (half-wave each)
  const int half = lane >> 5, e = lane & 31;
  for (int it = 0; it < 48; it++) {
    const int s = it * 2 + half;
    const int c = s / 6, l = s - c * 6;
    const int base = (v * NC + c) * NL + l;
    const int valid = ldmask(vval, base, bdt);
    const int neg = ldmask(negm, base, bdt);
    const int idx = lits[base];
    const u16* src = !valid ? (wsB + U_VARSB + NV * 64)
                            : (neg ? wsB + U_NEGB + idx * 64 : wsB + U_VARSB + idx * 64);
    const u32 val = *(const u32*)(src + (e << 1));
    *(u32*)(XsW + c * 392 + l * 64 + (e << 1)) = val;
  }

  // MFMA: M-tile = 16 clause rows, N = 128 ([W1v|W2v]), K = 384
  f32x4 acc[8];
#pragma unroll
  for (int nt = 0; nt < 8; nt++) acc[nt] = (f32x4){0.f, 0.f, 0.f, 0.f};
  for (int ks = 0; ks < 12; ks++) {
    const short8 a = *(const short8*)(XsW + col * 392 + ks * 32 + q8);
#pragma unroll
    for (int nt = 0; nt < 8; nt++) {
      const short8 b = *(const short8*)(wsB + U_BV + (nt * 16 + col) * 384 + ks * 32 + q8);
      acc[nt] = __builtin_amdgcn_mfma_f32_16x16x32_bf16(a, b, acc[nt], 0, 0, 0);
    }
  }

  // epilogue: h = sigmoid(C1+b1v) + C2 + b2v, row-normalize, clause padding
  float b1l[4], b2l[4], truel[4];
#pragma unroll
  for (int nt = 0; nt < 4; nt++) {
    const int d = nt * 16 + col;
    b1l[nt] = pbuf[PB_B1V + d];
    b2l[nt] = pbuf[PB_B2V + d];
    truel[nt] = ldbf(wsB, U_NEGB + NV * 64 + d);
  }
#pragma unroll
  for (int reg = 0; reg < 4; reg++) {
    const int c = quad * 4 + reg;
    float h[4], ss = 0.f;
#pragma unroll
    for (int nt = 0; nt < 4; nt++) {
      h[nt] = 1.0f / (1.0f + __expf(-(acc[nt][reg] + b1l[nt]))) + acc[nt + 4][reg] + b2l[nt];
      ss += h[nt] * h[nt];
    }
    ss += __shfl_xor(ss, 1, 64); ss += __shfl_xor(ss, 2, 64);
    ss += __shfl_xor(ss, 4, 64); ss += __shfl_xor(ss, 8, 64);
    const float sc = 1.0f / sqrtf(ss);
    const int valid = cvS[wv][c];
#pragma unroll
    for (int nt = 0; nt < 4; nt++) {
      const float o = valid ? h[nt] * sc : truel[nt];
      wsB[U_CE + (v * NC + c) * 64 + nt * 16 + col] = f2b(o);
    }
  }
}

// ---------- var combiner: 16 vars per block ----------
__global__ __launch_bounds__(256) void k_var(
    const void* __restrict__ vars, const void* __restrict__ cval,
    const float* __restrict__ pbuf, const int* __restrict__ flags,
    const u16* __restrict__ wsB, void* __restrict__ outv) {
  __shared__ __align__(16) u16 Xs[16 * 1032];
  __shared__ float ps[16][4];
  __shared__ int hcS[16];

  const int tid = threadIdx.x, lane = tid & 63, wv = tid >> 6;
  const int col = lane & 15, quad = lane >> 4, q8 = quad * 8;
  const int fdt = flags[0], bdt = flags[1];
  const int v0 = blockIdx.x * 16;

  // stage A: clause_emb rows v0..v0+15 (16 x 1024 bf16), 16-byte chunks
  for (int i = tid; i < 16 * 128; i += 256) {
    const int r = i >> 7, ch = i & 127;
    *(short8*)(Xs + r * 1032 + ch * 8) = *(const short8*)(wsB + U_CE + (v0 + r) * 1024 + ch * 8);
  }
  // has_clauses per var via ballot (tid -> (var u, clause c))
  {
    const int cv = ldmask(cval, v0 * NC + tid, bdt);
    const unsigned long long bal = __ballot(cv != 0);
    const int u = lane >> 4;
    if ((lane & 15) == 0) hcS[wv * 4 + u] = (int)((bal >> (u * 16)) & 0xFFFFull) != 0;
  }
  __syncthreads();

  // MFMA: M=16 vars, K=1024; wave w owns cols d in [w*16, w*16+16) via n-tiles {w, w+4}
  f32x4 acc1 = (f32x4){0.f, 0.f, 0.f, 0.f}, acc2 = (f32x4){0.f, 0.f, 0.f, 0.f};
  for (int ks = 0; ks < 32; ks++) {
    const short8 a = *(const short8*)(Xs + col * 1032 + ks * 32 + q8);
    const short8 b1 = *(const short8*)(wsB + U_BC + (wv * 16 + col) * 1024 + ks * 32 + q8);
    const short8 b2 = *(const short8*)(wsB + U_BC + ((wv + 4) * 16 + col) * 1024 + ks * 32 + q8);
    acc1 = __builtin_amdgcn_mfma_f32_16x16x32_bf16(a, b1, acc1, 0, 0, 0);
    acc2 = __builtin_amdgcn_mfma_f32_16x16x32_bf16(a, b2, acc2, 0, 0, 0);
  }

  const int d = wv * 16 + col;
  const float b1c_d = pbuf[PB_B1C + d], b2c_d = pbuf[PB_B2C + d];
  float h[4];
#pragma unroll
  for (int reg = 0; reg < 4; reg++) {
    h[reg] = 1.0f / (1.0f + __expf(-(acc1[reg] + b1c_d))) + acc2[reg] + b2c_d;
    float ssp = h[reg] * h[reg];
    ssp += __shfl_xor(ssp, 1, 64); ssp += __shfl_xor(ssp, 2, 64);
    ssp += __shfl_xor(ssp, 4, 64); ssp += __shfl_xor(ssp, 8, 64);
    if (col == 0) ps[quad * 4 + reg][wv] = ssp;
  }
  __syncthreads();
#pragma unroll
  for (int reg = 0; reg < 4; reg++) {
    const int r = quad * 4 + reg;       // var row within block
    const int v = v0 + r;
    const float tot = ps[r][0] + ps[r][1] + ps[r][2] + ps[r][3];
    float o = h[reg] * (1.0f / sqrtf(tot));
    const int oi = v * 64 + d;
    if (hcS[r]) {
      if (fdt) ((u16*)outv)[oi] = f2b(o);
      else ((float*)outv)[oi] = o;
    } else {
      if (fdt) ((u16*)outv)[oi] = ((const u16*)vars)[oi];
      else ((float*)outv)[oi] = ((const float*)vars)[oi];
    }
  }
}

extern "C" void kernel_launch(void* const* d_in, const int* in_sizes, int n_in,
                              void* d_out, int out_size, void* d_ws, size_t ws_size,
                              hipStream_t stream) {
  const void* vars = d_in[0];
  const int* lits = (const int*)d_in[1];
  const void* negm = d_in[2];
  const void* vval = d_in[3];
  const void* cvalid = d_in[4];
  const void* Wn = d_in[5];
  const void* bn = d_in[6];
  const void* femb = d_in[7];
  const void* W1v = d_in[8];
  const void* b1v = d_in[9];
  const void* W2v = d_in[10];
  const void* b2v = d_in[11];
  const void* W1c = d_in[12];
  const void* b1c = d_in[13];
  const void* W2c = d_in[14];
  const void* b2c = d_in[15];

  int* flags = (int*)d_ws;
  float* pbuf = (float*)((char*)d_ws + 256);
  u16* wsB = (u16*)d_ws;

  k_prep0<<<1, 256, 0, stream>>>(vars, vval, bn, femb, b1v, b2v, b1c, b2c, flags, pbuf, wsB);
  k_prepW<<<64, 256, 0, stream>>>(W1v, W2v, W1c, W2c, Wn, flags, wsB);
  k_cvt<<<NV * 64 / 256, 256, 0, stream>>>(vars, flags, wsB);
  k_negvar<<<(NV + 1 + 63) / 64, 256, 0, stream>>>(pbuf, wsB);
  k_clause<<<NV / 4, 256, 0, stream>>>(lits, negm, vval, cvalid, pbuf, flags, wsB);
  k_var<<<NV / 16, 256, 0, stream>>>(vars, cvalid, pbuf, flags, wsB, d_out);
}

// Round 5
// 281.167 us; speedup vs baseline: 5.1500x; 1.7574x over previous
//
#include <hip/hip_runtime.h>
#include <hip/hip_bf16.h>

#define NV 16384
#define NC 16
#define NL 6
#define ND 64

typedef unsigned short u16;
typedef unsigned int u32;
typedef __attribute__((ext_vector_type(8))) short short8;
typedef __attribute__((ext_vector_type(4))) float f32x4;

// ---- pbuf (fp32) offsets, pbuf = (float*)((char*)ws + 256) ----
#define PB_BN  0
#define PB_FE  64
#define PB_B1V 128
#define PB_B2V 192
#define PB_B1C 256
#define PB_B2C 320
// ---- bf16 regions, offsets in u16 elements from (u16*)ws ----
#define U_BV    896       // [128][384]  Bv[n][k]: n<64 -> W1v[k][n], n>=64 -> W2v[k][n-64]
#define U_BC    50048     // [128][1024] same for W1c/W2c
#define U_BN    181120    // [64][64]    Bn[n][k] = Wn[k][n]
#define U_VARSB 185216    // [NV+1][64]  bf16 vars; row NV = false_emb
#define U_NEGB  1233856   // [NV+1][64]  bf16 negvar; row NV = true_emb (== U_VARSB + (NV+1)*64)
#define U_CE    2282496   // [NV][16][64] bf16 clause_emb
#define U_FIDX  19059712  // [NV][96] u16 fused row index into unified vars/neg table

__device__ __forceinline__ float ldbf(const u16* p, int i) {
  return __uint_as_float(((u32)p[i]) << 16);
}
__device__ __forceinline__ u16 f2b(float f) {  // RNE f32->bf16
  u32 x = __float_as_uint(f);
  return (u16)((x + 0x7FFF + ((x >> 16) & 1)) >> 16);
}
__device__ __forceinline__ int ldmask(const void* p, int i, int bdt) {
  return bdt ? (int)((const signed char*)p)[i] : ((const int*)p)[i];
}
__device__ __forceinline__ float ldf(const void* p, int i, int fdt) {
  return fdt ? ldbf((const u16*)p, i) : ((const float*)p)[i];
}

// ---------- prep0: sniff dtypes, small fp32 params, varsB row NV ----------
__global__ __launch_bounds__(256) void k_prep0(
    const void* vars, const void* vval, const void* bn, const void* femb,
    const void* b1v, const void* b2v, const void* b1c, const void* b2c,
    int* flags, float* pbuf, u16* wsB) {
  __shared__ int sf;
  if (threadIdx.x == 0) {
    const u32* w = (const u32*)vars;
    int cnt = 0;
    for (int i = 0; i < 256; i++) {
      u32 e = (w[i] >> 7) & 0xFF;
      cnt += (e >= 0x6E && e <= 0x8E) ? 1 : 0;
    }
    int fdt = (cnt >= 192) ? 1 : 0;
    const u32* b = (const u32*)vval;
    int big = 0;
    for (int i = 0; i < 256; i++) big |= (b[i] > 1u) ? 1 : 0;
    flags[0] = fdt;
    flags[1] = big;
    sf = fdt;
  }
  __syncthreads();
  const int fdt = sf;
  const int tid = threadIdx.x;
  if (tid < 64) {
    const void* src[6] = {bn, femb, b1v, b2v, b1c, b2c};
    const int off[6] = {PB_BN, PB_FE, PB_B1V, PB_B2V, PB_B1C, PB_B2C};
    for (int j = 0; j < 6; j++) pbuf[off[j] + tid] = ldf(src[j], tid, fdt);
    wsB[U_VARSB + NV * 64 + tid] = fdt ? ((const u16*)femb)[tid] : f2b(((const float*)femb)[tid]);
  }
}

// ---------- prepW: transpose big weights to bf16 [n][k] ----------
__global__ __launch_bounds__(256) void k_prepW(
    const void* W1v, const void* W2v, const void* W1c, const void* W2c,
    const void* Wn, const int* flags, u16* wsB) {
  const int fdt = flags[0];
  for (int i = blockIdx.x * 256 + threadIdx.x; i < 184320; i += 64 * 256) {
    if (i < 49152) {
      int n = i / 384, k = i - n * 384;
      const void* src = (n < 64) ? W1v : W2v;
      wsB[U_BV + i] = f2b(ldf(src, k * 64 + (n & 63), fdt));
    } else if (i < 180224) {
      int j = i - 49152;
      int n = j / 1024, k = j - n * 1024;
      const void* src = (n < 64) ? W1c : W2c;
      wsB[U_BC + j] = f2b(ldf(src, k * 64 + (n & 63), fdt));
    } else {
      int j = i - 180224;
      int n = j >> 6, k = j & 63;
      wsB[U_BN + j] = f2b(ldf(Wn, k * 64 + n, fdt));
    }
  }
}

// ---------- cvt: vars -> bf16 varsB rows 0..NV-1 (8 elems/thread) ----------
__global__ __launch_bounds__(256) void k_cvt(const void* vars, const int* flags, u16* wsB) {
  const int fdt = flags[0];
  const int c8 = blockIdx.x * 256 + threadIdx.x;  // chunk of 8 elements
  u16 o[8];
  if (fdt) {
    *(short8*)o = ((const short8*)vars)[c8];
  } else {
    const float* f = (const float*)vars + c8 * 8;
#pragma unroll
    for (int j = 0; j < 8; j++) o[j] = f2b(f[j]);
  }
  *(short8*)(wsB + U_VARSB + c8 * 8) = *(short8*)o;
}

// ---------- fidx: fused gather row index per literal ----------
__global__ __launch_bounds__(256) void k_fidx(
    const int* __restrict__ lits, const void* __restrict__ negm,
    const void* __restrict__ vval, const int* __restrict__ flags,
    u16* __restrict__ wsB) {
  const int bdt = flags[1];
  const int i = blockIdx.x * 256 + threadIdx.x;  // 0 .. NV*96-1
  const int valid = ldmask(vval, i, bdt);
  const int neg = ldmask(negm, i, bdt);
  const int idx = lits[i];
  wsB[U_FIDX + i] = (u16)(valid ? (idx + (neg ? (NV + 1) : 0)) : NV);
}

// ---------- negvar via MFMA: negB[r] = varsB[r] @ Wn + bn (row NV -> true_emb) ----------
__global__ __launch_bounds__(256) void k_negvar(const float* pbuf, u16* wsB) {
  const int tid = threadIdx.x, lane = tid & 63, wv = tid >> 6;
  const int col = lane & 15, quad = lane >> 4, q8 = quad * 8;
  const int rowbase = blockIdx.x * 64 + wv * 16;
  f32x4 acc[4];
#pragma unroll
  for (int nt = 0; nt < 4; nt++) acc[nt] = (f32x4){0.f, 0.f, 0.f, 0.f};
  const int arow = min(rowbase + col, NV);
#pragma unroll
  for (int ks = 0; ks < 2; ks++) {
    const short8 a = *(const short8*)(wsB + U_VARSB + arow * 64 + ks * 32 + q8);
#pragma unroll
    for (int nt = 0; nt < 4; nt++) {
      const short8 b = *(const short8*)(wsB + U_BN + (nt * 16 + col) * 64 + ks * 32 + q8);
      acc[nt] = __builtin_amdgcn_mfma_f32_16x16x32_bf16(a, b, acc[nt], 0, 0, 0);
    }
  }
#pragma unroll
  for (int reg = 0; reg < 4; reg++) {
    const int r = rowbase + quad * 4 + reg;
    if (r <= NV) {
#pragma unroll
      for (int nt = 0; nt < 4; nt++) {
        const int d = nt * 16 + col;
        wsB[U_NEGB + r * 64 + d] = f2b(acc[nt][reg] + pbuf[PB_BN + d]);
      }
    }
  }
}

// ---------- clause combiner: register-gathered MFMA, 2 vars/wave, no LDS ----------
__global__ __launch_bounds__(256) void k_clause(
    const void* __restrict__ cval, const float* __restrict__ pbuf,
    const int* __restrict__ flags, u16* __restrict__ wsB) {
  const int tid = threadIdx.x, lane = tid & 63, wv = tid >> 6;
  const int col = lane & 15, quad = lane >> 4, q8 = quad * 8;
  const int bdt = flags[1];
  const int v0 = (blockIdx.x * 4 + wv) * 2;  // this wave: vars v0, v0+1

  // per-lane row indices (6 per var) for A-fragments of row m=col
  int r0[6], r1[6];
#pragma unroll
  for (int l = 0; l < 6; l++) {
    r0[l] = wsB[U_FIDX + v0 * 96 + col * 6 + l];
    r1[l] = wsB[U_FIDX + (v0 + 1) * 96 + col * 6 + l];
  }

  // clause-valid masks via ballot: lanes 0..15 -> v0 clauses, 16..31 -> v1
  int cv = 0;
  if (lane < 32) cv = ldmask(cval, (v0 + (lane >> 4)) * NC + (lane & 15), bdt);
  const unsigned long long bal = __ballot(cv != 0);
  const u32 vmask[2] = {(u32)(bal & 0xFFFFull), (u32)((bal >> 16) & 0xFFFFull)};

  f32x4 acc0[8], acc1[8];
#pragma unroll
  for (int nt = 0; nt < 8; nt++) {
    acc0[nt] = (f32x4){0.f, 0.f, 0.f, 0.f};
    acc1[nt] = (f32x4){0.f, 0.f, 0.f, 0.f};
  }
#pragma unroll
  for (int ks = 0; ks < 12; ks++) {
    const int off = (ks & 1) * 32 + q8;
    const short8 a0 = *(const short8*)(wsB + U_VARSB + r0[ks >> 1] * 64 + off);
    const short8 a1 = *(const short8*)(wsB + U_VARSB + r1[ks >> 1] * 64 + off);
#pragma unroll
    for (int nt = 0; nt < 8; nt++) {
      const short8 b = *(const short8*)(wsB + U_BV + (nt * 16 + col) * 384 + ks * 32 + q8);
      acc0[nt] = __builtin_amdgcn_mfma_f32_16x16x32_bf16(a0, b, acc0[nt], 0, 0, 0);
      acc1[nt] = __builtin_amdgcn_mfma_f32_16x16x32_bf16(a1, b, acc1[nt], 0, 0, 0);
    }
  }

  // epilogue
  float b1l[4], b2l[4], truel[4];
#pragma unroll
  for (int nt = 0; nt < 4; nt++) {
    const int d = nt * 16 + col;
    b1l[nt] = pbuf[PB_B1V + d];
    b2l[nt] = pbuf[PB_B2V + d];
    truel[nt] = ldbf(wsB, U_NEGB + NV * 64 + d);
  }
#pragma unroll
  for (int u = 0; u < 2; u++) {
    const f32x4* acc = u ? acc1 : acc0;
    const int v = v0 + u;
#pragma unroll
    for (int reg = 0; reg < 4; reg++) {
      const int c = quad * 4 + reg;
      float h[4], ss = 0.f;
#pragma unroll
      for (int nt = 0; nt < 4; nt++) {
        h[nt] = 1.0f / (1.0f + __expf(-(acc[nt][reg] + b1l[nt]))) + acc[nt + 4][reg] + b2l[nt];
        ss += h[nt] * h[nt];
      }
      ss += __shfl_xor(ss, 1, 64); ss += __shfl_xor(ss, 2, 64);
      ss += __shfl_xor(ss, 4, 64); ss += __shfl_xor(ss, 8, 64);
      const float sc = 1.0f / sqrtf(ss);
      const int valid = (vmask[u] >> c) & 1;
#pragma unroll
      for (int nt = 0; nt < 4; nt++) {
        const float o = valid ? h[nt] * sc : truel[nt];
        wsB[U_CE + (v * NC + c) * 64 + nt * 16 + col] = f2b(o);
      }
    }
  }
}

// ---------- var combiner: 16 vars per block ----------
__global__ __launch_bounds__(256) void k_var(
    const void* __restrict__ vars, const void* __restrict__ cval,
    const float* __restrict__ pbuf, const int* __restrict__ flags,
    const u16* __restrict__ wsB, void* __restrict__ outv) {
  __shared__ __align__(16) u16 Xs[16 * 1032];
  __shared__ float ps[16][4];
  __shared__ int hcS[16];

  const int tid = threadIdx.x, lane = tid & 63, wv = tid >> 6;
  const int col = lane & 15, quad = lane >> 4, q8 = quad * 8;
  const int fdt = flags[0], bdt = flags[1];
  const int v0 = blockIdx.x * 16;

  // stage clause_emb rows v0..v0+15 (16 x 1024 bf16), 16-byte chunks
  for (int i = tid; i < 16 * 128; i += 256) {
    const int r = i >> 7, ch = i & 127;
    *(short8*)(Xs + r * 1032 + ch * 8) = *(const short8*)(wsB + U_CE + (v0 + r) * 1024 + ch * 8);
  }
  {
    const int cv = ldmask(cval, v0 * NC + tid, bdt);
    const unsigned long long bal = __ballot(cv != 0);
    const int u = lane >> 4;
    if ((lane & 15) == 0) hcS[wv * 4 + u] = (int)((bal >> (u * 16)) & 0xFFFFull) != 0;
  }
  __syncthreads();

  f32x4 acc1 = (f32x4){0.f, 0.f, 0.f, 0.f}, acc2 = (f32x4){0.f, 0.f, 0.f, 0.f};
  for (int ks = 0; ks < 32; ks++) {
    const short8 a = *(const short8*)(Xs + col * 1032 + ks * 32 + q8);
    const short8 b1 = *(const short8*)(wsB + U_BC + (wv * 16 + col) * 1024 + ks * 32 + q8);
    const short8 b2 = *(const short8*)(wsB + U_BC + ((wv + 4) * 16 + col) * 1024 + ks * 32 + q8);
    acc1 = __builtin_amdgcn_mfma_f32_16x16x32_bf16(a, b1, acc1, 0, 0, 0);
    acc2 = __builtin_amdgcn_mfma_f32_16x16x32_bf16(a, b2, acc2, 0, 0, 0);
  }

  const int d = wv * 16 + col;
  const float b1c_d = pbuf[PB_B1C + d], b2c_d = pbuf[PB_B2C + d];
  float h[4];
#pragma unroll
  for (int reg = 0; reg < 4; reg++) {
    h[reg] = 1.0f / (1.0f + __expf(-(acc1[reg] + b1c_d))) + acc2[reg] + b2c_d;
    float ssp = h[reg] * h[reg];
    ssp += __shfl_xor(ssp, 1, 64); ssp += __shfl_xor(ssp, 2, 64);
    ssp += __shfl_xor(ssp, 4, 64); ssp += __shfl_xor(ssp, 8, 64);
    if (col == 0) ps[quad * 4 + reg][wv] = ssp;
  }
  __syncthreads();
#pragma unroll
  for (int reg = 0; reg < 4; reg++) {
    const int r = quad * 4 + reg;
    const int v = v0 + r;
    const float tot = ps[r][0] + ps[r][1] + ps[r][2] + ps[r][3];
    float o = h[reg] * (1.0f / sqrtf(tot));
    const int oi = v * 64 + d;
    if (hcS[r]) {
      if (fdt) ((u16*)outv)[oi] = f2b(o);
      else ((float*)outv)[oi] = o;
    } else {
      if (fdt) ((u16*)outv)[oi] = ((const u16*)vars)[oi];
      else ((float*)outv)[oi] = ((const float*)vars)[oi];
    }
  }
}

extern "C" void kernel_launch(void* const* d_in, const int* in_sizes, int n_in,
                              void* d_out, int out_size, void* d_ws, size_t ws_size,
                              hipStream_t stream) {
  const void* vars = d_in[0];
  const int* lits = (const int*)d_in[1];
  const void* negm = d_in[2];
  const void* vval = d_in[3];
  const void* cvalid = d_in[4];
  const void* Wn = d_in[5];
  const void* bn = d_in[6];
  const void* femb = d_in[7];
  const void* W1v = d_in[8];
  const void* b1v = d_in[9];
  const void* W2v = d_in[10];
  const void* b2v = d_in[11];
  const void* W1c = d_in[12];
  const void* b1c = d_in[13];
  const void* W2c = d_in[14];
  const void* b2c = d_in[15];

  int* flags = (int*)d_ws;
  float* pbuf = (float*)((char*)d_ws + 256);
  u16* wsB = (u16*)d_ws;

  k_prep0<<<1, 256, 0, stream>>>(vars, vval, bn, femb, b1v, b2v, b1c, b2c, flags, pbuf, wsB);
  k_prepW<<<64, 256, 0, stream>>>(W1v, W2v, W1c, W2c, Wn, flags, wsB);
  k_cvt<<<NV * 64 / 8 / 256, 256, 0, stream>>>(vars, flags, wsB);
  k_fidx<<<NV * 96 / 256, 256, 0, stream>>>(lits, negm, vval, flags, wsB);
  k_negvar<<<(NV + 1 + 63) / 64, 256, 0, stream>>>(pbuf, wsB);
  k_clause<<<NV / 8, 256, 0, stream>>>(cvalid, pbuf, flags, wsB);
  k_var<<<NV / 16, 256, 0, stream>>>(vars, cvalid, pbuf, flags, wsB, d_out);
}

// Round 6
// 185.653 us; speedup vs baseline: 7.7996x; 1.5145x over previous
//
#include <hip/hip_runtime.h>
#include <hip/hip_bf16.h>

#define NV 16384
#define NC 16
#define NL 6
#define ND 64

typedef unsigned short u16;
typedef unsigned int u32;
typedef __attribute__((ext_vector_type(8))) short short8;
typedef __attribute__((ext_vector_type(4))) float f32x4;

// ---- pbuf (fp32) offsets, pbuf = (float*)((char*)ws + 256) ----
#define PB_BN  0
#define PB_FE  64
#define PB_B1V 128
#define PB_B2V 192
#define PB_B1C 256
#define PB_B2C 320
// ---- bf16 regions, offsets in u16 elements from (u16*)ws ----
#define U_BV    896       // [128][384]  Bv[n][k]: n<64 -> W1v[k][n], n>=64 -> W2v[k][n-64]
#define U_BC    50048     // [128][1024] same for W1c/W2c
#define U_BN    181120    // [64][64]    Bn[n][k] = Wn[k][n]
#define U_VARSB 185216    // [NV+1][64]  bf16 vars; row NV = false_emb
#define U_NEGB  1233856   // [NV+1][64]  bf16 negvar; row NV = true_emb (== U_VARSB + (NV+1)*64)
#define U_CE    2282496   // [NV][16][64] bf16 clause_emb
#define U_FIDX  19059712  // [NV][96] u16 fused row index into unified vars/neg table

__device__ __forceinline__ float ldbf(const u16* p, int i) {
  return __uint_as_float(((u32)p[i]) << 16);
}
__device__ __forceinline__ u16 f2b(float f) {  // RNE f32->bf16
  u32 x = __float_as_uint(f);
  return (u16)((x + 0x7FFF + ((x >> 16) & 1)) >> 16);
}
__device__ __forceinline__ int ldmask(const void* p, int i, int bdt) {
  return bdt ? (int)((const signed char*)p)[i] : ((const int*)p)[i];
}
__device__ __forceinline__ float ldf(const void* p, int i, int fdt) {
  return fdt ? ldbf((const u16*)p, i) : ((const float*)p)[i];
}

// ---------- merged prep: sniff (per-block) + params + W transpose + cvt + fidx ----------
// grid layout: block 0 = params/flags; 1..64 = weight transpose; 65..576 = cvt;
// 577..2112 = fidx (4 literals/thread).
__global__ __launch_bounds__(256) void k_prep(
    const void* vars, const int* __restrict__ lits, const void* negm, const void* vval,
    const void* Wn, const void* bn, const void* femb,
    const void* W1v, const void* b1v, const void* W2v, const void* b2v,
    const void* W1c, const void* b1c, const void* W2c, const void* b2c,
    int* flags, float* pbuf, u16* wsB) {
  __shared__ int s_cnt[4], s_big[4];
  const int t = threadIdx.x;
  {
    const u32 w = ((const u32*)vars)[t];
    const u32 e = (w >> 7) & 0xFF;
    const unsigned long long bal = __ballot(e >= 0x6E && e <= 0x8E);
    const u32 bw = ((const u32*)vval)[t];
    const unsigned long long bb = __ballot(bw > 1u);
    if ((t & 63) == 0) { s_cnt[t >> 6] = __popcll(bal); s_big[t >> 6] = (bb != 0ull); }
  }
  __syncthreads();
  const int fdt = (s_cnt[0] + s_cnt[1] + s_cnt[2] + s_cnt[3]) >= 192;
  const int bdt = (s_big[0] | s_big[1] | s_big[2] | s_big[3]);
  const int bid = blockIdx.x;

  if (bid == 0) {
    if (t == 0) { flags[0] = fdt; flags[1] = bdt; }
    if (t < 64) {
      const void* src[6] = {bn, femb, b1v, b2v, b1c, b2c};
      const int off[6] = {PB_BN, PB_FE, PB_B1V, PB_B2V, PB_B1C, PB_B2C};
      for (int j = 0; j < 6; j++) pbuf[off[j] + t] = ldf(src[j], t, fdt);
      wsB[U_VARSB + NV * 64 + t] = fdt ? ((const u16*)femb)[t] : f2b(((const float*)femb)[t]);
    }
  } else if (bid < 65) {
    for (int i = (bid - 1) * 256 + t; i < 184320; i += 64 * 256) {
      if (i < 49152) {
        int n = i / 384, k = i - n * 384;
        const void* src = (n < 64) ? W1v : W2v;
        wsB[U_BV + i] = f2b(ldf(src, k * 64 + (n & 63), fdt));
      } else if (i < 180224) {
        int j = i - 49152;
        int n = j / 1024, k = j - n * 1024;
        const void* src = (n < 64) ? W1c : W2c;
        wsB[U_BC + j] = f2b(ldf(src, k * 64 + (n & 63), fdt));
      } else {
        int j = i - 180224;
        int n = j >> 6, k = j & 63;
        wsB[U_BN + j] = f2b(ldf(Wn, k * 64 + n, fdt));
      }
    }
  } else if (bid < 577) {
    const int c8 = (bid - 65) * 256 + t;  // chunk of 8 elements
    u16 o[8];
    if (fdt) {
      *(short8*)o = ((const short8*)vars)[c8];
    } else {
      const float* f = (const float*)vars + c8 * 8;
#pragma unroll
      for (int j = 0; j < 8; j++) o[j] = f2b(f[j]);
    }
    *(short8*)(wsB + U_VARSB + c8 * 8) = *(short8*)o;
  } else {
    const int i0 = ((bid - 577) * 256 + t) * 4;
    u16 o[4];
#pragma unroll
    for (int j = 0; j < 4; j++) {
      const int i = i0 + j;
      const int valid = ldmask(vval, i, bdt);
      const int neg = ldmask(negm, i, bdt);
      const int idx = lits[i];
      o[j] = (u16)(valid ? (idx + (neg ? (NV + 1) : 0)) : NV);
    }
    *(ushort4*)(wsB + U_FIDX + i0) = *(ushort4*)o;
  }
}

// ---------- negvar via MFMA: negB[r] = varsB[r] @ Wn + bn (row NV -> true_emb) ----------
__global__ __launch_bounds__(256) void k_negvar(const float* pbuf, u16* wsB) {
  const int tid = threadIdx.x, lane = tid & 63, wv = tid >> 6;
  const int col = lane & 15, quad = lane >> 4, q8 = quad * 8;
  const int rowbase = blockIdx.x * 64 + wv * 16;
  f32x4 acc[4];
#pragma unroll
  for (int nt = 0; nt < 4; nt++) acc[nt] = (f32x4){0.f, 0.f, 0.f, 0.f};
  const int arow = min(rowbase + col, NV);
#pragma unroll
  for (int ks = 0; ks < 2; ks++) {
    const short8 a = *(const short8*)(wsB + U_VARSB + arow * 64 + ks * 32 + q8);
#pragma unroll
    for (int nt = 0; nt < 4; nt++) {
      const short8 b = *(const short8*)(wsB + U_BN + (nt * 16 + col) * 64 + ks * 32 + q8);
      acc[nt] = __builtin_amdgcn_mfma_f32_16x16x32_bf16(a, b, acc[nt], 0, 0, 0);
    }
  }
#pragma unroll
  for (int reg = 0; reg < 4; reg++) {
    const int r = rowbase + quad * 4 + reg;
    if (r <= NV) {
#pragma unroll
      for (int nt = 0; nt < 4; nt++) {
        const int d = nt * 16 + col;
        wsB[U_NEGB + r * 64 + d] = f2b(acc[nt][reg] + pbuf[PB_BN + d]);
      }
    }
  }
}

// ---------- clause combiner: LDS-staged B, register-gathered A, 4 vars/wave ----------
// 512 threads (8 waves), 32 vars/block; B tile [128][192] staged per K-half.
__global__ __launch_bounds__(512) void k_clause(
    const void* __restrict__ cval, const float* __restrict__ pbuf,
    const int* __restrict__ flags, u16* __restrict__ wsB) {
  __shared__ __align__(16) u16 Bs[128 * 200];  // 192 cols + 8 pad (50 KB)

  const int tid = threadIdx.x, lane = tid & 63, wv = tid >> 6;
  const int col = lane & 15, quad = lane >> 4, q8 = quad * 8;
  const int bdt = flags[1];
  const int gw = blockIdx.x * 8 + wv;     // global wave id
  const int vbase = gw * 4;               // 4 vars per wave (2 pairs)

  // per-lane gather row indices: r_[p][u][l]
  int r_[2][2][6];
#pragma unroll
  for (int p = 0; p < 2; p++)
#pragma unroll
    for (int u = 0; u < 2; u++) {
      const int v = vbase + p * 2 + u;
#pragma unroll
      for (int l = 0; l < 6; l++) r_[p][u][l] = wsB[U_FIDX + v * 96 + col * 6 + l];
    }

  // clause-valid: 64 lanes <-> 4 vars x 16 clauses
  const int cv = ldmask(cval, vbase * 16 + lane, bdt);
  const unsigned long long bal = __ballot(cv != 0);

  f32x4 acc[2][2][8];
#pragma unroll
  for (int p = 0; p < 2; p++)
#pragma unroll
    for (int u = 0; u < 2; u++)
#pragma unroll
      for (int nt = 0; nt < 8; nt++) acc[p][u][nt] = (f32x4){0.f, 0.f, 0.f, 0.f};

  for (int h = 0; h < 2; h++) {
    if (h) __syncthreads();  // protect Bs from overwrite while in use
    // stage B half: [128][192] from U_BV[n][h*192 + k']
#pragma unroll
    for (int i = 0; i < 6; i++) {
      const int c = i * 512 + tid;          // 3072 chunks of 8 u16
      const int n = c / 24, k8 = (c % 24) * 8;
      *(short8*)(Bs + n * 200 + k8) = *(const short8*)(wsB + U_BV + n * 384 + h * 192 + k8);
    }
    __syncthreads();

#pragma unroll
    for (int ks = 0; ks < 6; ks++) {
      const int off = (ks & 1) * 32 + q8;
      const int l = h * 3 + (ks >> 1);
      short8 a[2][2];
#pragma unroll
      for (int p = 0; p < 2; p++)
#pragma unroll
        for (int u = 0; u < 2; u++)
          a[p][u] = *(const short8*)(wsB + U_VARSB + r_[p][u][l] * 64 + off);
#pragma unroll
      for (int nt = 0; nt < 8; nt++) {
        const short8 b = *(const short8*)(Bs + (nt * 16 + col) * 200 + ks * 32 + q8);
#pragma unroll
        for (int p = 0; p < 2; p++)
#pragma unroll
          for (int u = 0; u < 2; u++)
            acc[p][u][nt] = __builtin_amdgcn_mfma_f32_16x16x32_bf16(a[p][u], b, acc[p][u][nt], 0, 0, 0);
      }
    }
  }

  // epilogue
  float b1l[4], b2l[4], truel[4];
#pragma unroll
  for (int nt = 0; nt < 4; nt++) {
    const int d = nt * 16 + col;
    b1l[nt] = pbuf[PB_B1V + d];
    b2l[nt] = pbuf[PB_B2V + d];
    truel[nt] = ldbf(wsB, U_NEGB + NV * 64 + d);
  }
#pragma unroll
  for (int p = 0; p < 2; p++)
#pragma unroll
    for (int u = 0; u < 2; u++) {
      const int v = vbase + p * 2 + u;
      const u32 vmask = (u32)((bal >> ((p * 2 + u) * 16)) & 0xFFFFull);
#pragma unroll
      for (int reg = 0; reg < 4; reg++) {
        const int c = quad * 4 + reg;
        float h[4], ss = 0.f;
#pragma unroll
        for (int nt = 0; nt < 4; nt++) {
          h[nt] = 1.0f / (1.0f + __expf(-(acc[p][u][nt][reg] + b1l[nt]))) + acc[p][u][nt + 4][reg] + b2l[nt];
          ss += h[nt] * h[nt];
        }
        ss += __shfl_xor(ss, 1, 64); ss += __shfl_xor(ss, 2, 64);
        ss += __shfl_xor(ss, 4, 64); ss += __shfl_xor(ss, 8, 64);
        const float sc = 1.0f / sqrtf(ss);
        const int valid = (vmask >> c) & 1;
#pragma unroll
        for (int nt = 0; nt < 4; nt++) {
          const float o = valid ? h[nt] * sc : truel[nt];
          wsB[U_CE + (v * NC + c) * 64 + nt * 16 + col] = f2b(o);
        }
      }
    }
}

// ---------- var combiner: 16 vars per block ----------
__global__ __launch_bounds__(256) void k_var(
    const void* __restrict__ vars, const void* __restrict__ cval,
    const float* __restrict__ pbuf, const int* __restrict__ flags,
    const u16* __restrict__ wsB, void* __restrict__ outv) {
  __shared__ __align__(16) u16 Xs[16 * 1032];
  __shared__ float ps[16][4];
  __shared__ int hcS[16];

  const int tid = threadIdx.x, lane = tid & 63, wv = tid >> 6;
  const int col = lane & 15, quad = lane >> 4, q8 = quad * 8;
  const int fdt = flags[0], bdt = flags[1];
  const int v0 = blockIdx.x * 16;

  for (int i = tid; i < 16 * 128; i += 256) {
    const int r = i >> 7, ch = i & 127;
    *(short8*)(Xs + r * 1032 + ch * 8) = *(const short8*)(wsB + U_CE + (v0 + r) * 1024 + ch * 8);
  }
  {
    const int cv = ldmask(cval, v0 * NC + tid, bdt);
    const unsigned long long bal = __ballot(cv != 0);
    const int u = lane >> 4;
    if ((lane & 15) == 0) hcS[wv * 4 + u] = (int)((bal >> (u * 16)) & 0xFFFFull) != 0;
  }
  __syncthreads();

  f32x4 acc1 = (f32x4){0.f, 0.f, 0.f, 0.f}, acc2 = (f32x4){0.f, 0.f, 0.f, 0.f};
  for (int ks = 0; ks < 32; ks++) {
    const short8 a = *(const short8*)(Xs + col * 1032 + ks * 32 + q8);
    const short8 b1 = *(const short8*)(wsB + U_BC + (wv * 16 + col) * 1024 + ks * 32 + q8);
    const short8 b2 = *(const short8*)(wsB + U_BC + ((wv + 4) * 16 + col) * 1024 + ks * 32 + q8);
    acc1 = __builtin_amdgcn_mfma_f32_16x16x32_bf16(a, b1, acc1, 0, 0, 0);
    acc2 = __builtin_amdgcn_mfma_f32_16x16x32_bf16(a, b2, acc2, 0, 0, 0);
  }

  const int d = wv * 16 + col;
  const float b1c_d = pbuf[PB_B1C + d], b2c_d = pbuf[PB_B2C + d];
  float h[4];
#pragma unroll
  for (int reg = 0; reg < 4; reg++) {
    h[reg] = 1.0f / (1.0f + __expf(-(acc1[reg] + b1c_d))) + acc2[reg] + b2c_d;
    float ssp = h[reg] * h[reg];
    ssp += __shfl_xor(ssp, 1, 64); ssp += __shfl_xor(ssp, 2, 64);
    ssp += __shfl_xor(ssp, 4, 64); ssp += __shfl_xor(ssp, 8, 64);
    if (col == 0) ps[quad * 4 + reg][wv] = ssp;
  }
  __syncthreads();
#pragma unroll
  for (int reg = 0; reg < 4; reg++) {
    const int r = quad * 4 + reg;
    const int v = v0 + r;
    const float tot = ps[r][0] + ps[r][1] + ps[r][2] + ps[r][3];
    float o = h[reg] * (1.0f / sqrtf(tot));
    const int oi = v * 64 + d;
    if (hcS[r]) {
      if (fdt) ((u16*)outv)[oi] = f2b(o);
      else ((float*)outv)[oi] = o;
    } else {
      if (fdt) ((u16*)outv)[oi] = ((const u16*)vars)[oi];
      else ((float*)outv)[oi] = ((const float*)vars)[oi];
    }
  }
}

extern "C" void kernel_launch(void* const* d_in, const int* in_sizes, int n_in,
                              void* d_out, int out_size, void* d_ws, size_t ws_size,
                              hipStream_t stream) {
  const void* vars = d_in[0];
  const int* lits = (const int*)d_in[1];
  const void* negm = d_in[2];
  const void* vval = d_in[3];
  const void* cvalid = d_in[4];
  const void* Wn = d_in[5];
  const void* bn = d_in[6];
  const void* femb = d_in[7];
  const void* W1v = d_in[8];
  const void* b1v = d_in[9];
  const void* W2v = d_in[10];
  const void* b2v = d_in[11];
  const void* W1c = d_in[12];
  const void* b1c = d_in[13];
  const void* W2c = d_in[14];
  const void* b2c = d_in[15];

  int* flags = (int*)d_ws;
  float* pbuf = (float*)((char*)d_ws + 256);
  u16* wsB = (u16*)d_ws;

  k_prep<<<2113, 256, 0, stream>>>(vars, lits, negm, vval, Wn, bn, femb,
                                   W1v, b1v, W2v, b2v, W1c, b1c, W2c, b2c,
                                   flags, pbuf, wsB);
  k_negvar<<<(NV + 1 + 63) / 64, 256, 0, stream>>>(pbuf, wsB);
  k_clause<<<NV / 32, 512, 0, stream>>>(cvalid, pbuf, flags, wsB);
  k_var<<<NV / 16, 256, 0, stream>>>(vars, cvalid, pbuf, flags, wsB, d_out);
}